// Round 4
// baseline (682.139 us; speedup 1.0000x reference)
//
#include <hip/hip_runtime.h>

#define NMAT 2048
#define KATTR 64
#define CAP 128
#define NITER 10

typedef unsigned short ushort8v __attribute__((ext_vector_type(8)));
typedef unsigned short ushort4v __attribute__((ext_vector_type(4)));

// bf16 round-to-nearest-even (values finite here; NaN path irrelevant)
__device__ __forceinline__ unsigned short f2bf(float f) {
  unsigned u = __float_as_uint(f);
  return (unsigned short)((u + 0x7fff + ((u >> 16) & 1)) >> 16);
}
__device__ __forceinline__ float bf2f(unsigned short b) {
  return __uint_as_float((unsigned)b << 16);
}
// swizzled LDS dword index for the 4-row interleaved T1 tile: keeps phase A's
// transposed b128 writes bank-balanced while phase B's random-k b128 gathers
// stay ~uniform over bank groups.
__device__ __forceinline__ int swz(int c) { return 4 * c + (((c >> 3) & 7) << 2); }

// --------------------------------------------------------------------------
// Build padded adjacency (ELL) lists for pattern(A). B = (A*1/A^2)*A == (A!=0).
// A is symmetric (max(A,A^T)) so row pattern == column pattern (B^T == B).
// --------------------------------------------------------------------------
__global__ __launch_bounds__(256) void k_build(
    const float* __restrict__ A, unsigned short* __restrict__ idx,
    unsigned short* __restrict__ idxT, int* __restrict__ cnt) {
  __shared__ int lcnt;
  int r = blockIdx.x;
  if (threadIdx.x == 0) lcnt = 0;
  __syncthreads();
  const float* row = A + (size_t)r * NMAT;
  for (int c = threadIdx.x; c < NMAT; c += 256) {
    if (row[c] != 0.0f) {
      int p = atomicAdd(&lcnt, 1);
      if (p < CAP) {
        idx[r * CAP + p] = (unsigned short)c;
        if (idxT) idxT[(size_t)p * NMAT + r] = (unsigned short)c;
      }
    }
  }
  __syncthreads();
  if (threadIdx.x == 0) cnt[r] = lcnt < CAP ? lcnt : CAP;
}

// ------------------- row L2-normalize (one wave per row) -------------------
__global__ __launch_bounds__(256) void k_norm(const float* __restrict__ Nin,
                                              float* __restrict__ Nout) {
  int row = blockIdx.x * 4 + (threadIdx.x >> 6);
  int lane = threadIdx.x & 63;
  float v = Nin[(size_t)row * KATTR + lane];
  float ss = v * v;
#pragma unroll
  for (int o = 32; o > 0; o >>= 1) ss += __shfl_xor(ss, o);
  float nrm = sqrtf(ss);
  Nout[(size_t)row * KATTR + lane] = (nrm > 0.f) ? v / nrm : 0.f;
}

// ------------------- C = B @ Nn : gather-sum of attribute rows -------------
__global__ void k_gatherN(const unsigned short* __restrict__ idx,
                          const int* __restrict__ cnt,
                          const float* __restrict__ Nn,
                          float* __restrict__ C) {
  int i = blockIdx.x;
  int lane = threadIdx.x;  // blockDim = 64
  int nn = cnt[i];
  const unsigned short* ip = idx + i * CAP;
  float acc = 0.f;
  for (int t = 0; t < nn; ++t) {
    int k = ip[t];
    acc += Nn[(size_t)k * KATTR + lane];
  }
  C[(size_t)i * KATTR + lane] = acc;
}

// ------------------- Ht = H^T (tiled transpose) ----------------------------
__global__ __launch_bounds__(256) void k_transpose(const float* __restrict__ H,
                                                   float* __restrict__ Ht) {
  __shared__ float tile[64][65];
  int j0 = blockIdx.x * 64;
  int i0 = blockIdx.y * 64;
  int c = threadIdx.x & 63;
  int r0 = threadIdx.x >> 6;
  for (int r = r0; r < 64; r += 4)
    tile[r][c] = H[(size_t)(j0 + r) * NMAT + i0 + c];
  __syncthreads();
  for (int r = r0; r < 64; r += 4)
    Ht[(size_t)(i0 + r) * NMAT + j0 + c] = tile[c][r];
}

// --------------------------------------------------------------------------
// q[i,j] = Nm>0&dm>0 ? Nm*rsqrt(Nm*dm) : 0; also M0 = bf16(q * Ht).
// --------------------------------------------------------------------------
__global__ __launch_bounds__(256) void k_q(
    const float* __restrict__ N1n, const float* __restrict__ C1,
    const float* __restrict__ N2n, const float* __restrict__ C2,
    const float* __restrict__ Ht, float* __restrict__ q,
    unsigned short* __restrict__ M) {
  __shared__ float sA[64][68];
  __shared__ float sB[64][68];
  int i0 = blockIdx.y * 64, j0 = blockIdx.x * 64;
  int c = threadIdx.x & 63, r0 = threadIdx.x >> 6;
  int tx = threadIdx.x & 15, ty = threadIdx.x >> 4;

  float nmv[4][4] = {};
  float dmv[4][4] = {};

  for (int r = r0; r < 64; r += 4) {
    sA[c][r] = N1n[(size_t)(i0 + r) * KATTR + c];
    sB[c][r] = N2n[(size_t)(j0 + r) * KATTR + c];
  }
  __syncthreads();
#pragma unroll 4
  for (int k = 0; k < 64; ++k) {
    float4 a = *(const float4*)&sA[k][ty * 4];
    float4 b = *(const float4*)&sB[k][tx * 4];
    float av[4] = {a.x, a.y, a.z, a.w};
    float bv[4] = {b.x, b.y, b.z, b.w};
#pragma unroll
    for (int ii = 0; ii < 4; ++ii)
#pragma unroll
      for (int jj = 0; jj < 4; ++jj)
        nmv[ii][jj] = fmaf(av[ii], bv[jj], nmv[ii][jj]);
  }
  __syncthreads();
  for (int r = r0; r < 64; r += 4) {
    sA[c][r] = C1[(size_t)(i0 + r) * KATTR + c];
    sB[c][r] = C2[(size_t)(j0 + r) * KATTR + c];
  }
  __syncthreads();
#pragma unroll 4
  for (int k = 0; k < 64; ++k) {
    float4 a = *(const float4*)&sA[k][ty * 4];
    float4 b = *(const float4*)&sB[k][tx * 4];
    float av[4] = {a.x, a.y, a.z, a.w};
    float bv[4] = {b.x, b.y, b.z, b.w};
#pragma unroll
    for (int ii = 0; ii < 4; ++ii)
#pragma unroll
      for (int jj = 0; jj < 4; ++jj)
        dmv[ii][jj] = fmaf(av[ii], bv[jj], dmv[ii][jj]);
  }

#pragma unroll
  for (int ii = 0; ii < 4; ++ii) {
    int i = i0 + ty * 4 + ii;
    size_t base = (size_t)i * NMAT + j0 + tx * 4;
    float4 hv = *(const float4*)&Ht[base];
    float hvv[4] = {hv.x, hv.y, hv.z, hv.w};
    float qv[4];
    ushort4v mv;
#pragma unroll
    for (int jj = 0; jj < 4; ++jj) {
      float nmx = nmv[ii][jj];
      float D = nmx * dmv[ii][jj];
      float qq = (D > 0.f) ? nmx * rsqrtf(D) : 0.f;
      qv[jj] = qq;
      mv[jj] = f2bf(qq * hvv[jj]);
    }
    *(float4*)&q[base] = make_float4(qv[0], qv[1], qv[2], qv[3]);
    *(ushort4v*)&M[base] = mv;
  }
}

// --------------------------------------------------------------------------
// One full iteration, fused. Block owns rows i0..i0+3.
// Phase A: T1[i0..i0+3, :] = sum_{k in adj1(i)} Min[k, :]  gathered from
//          bf16 (in32=0) or fp32 (in32=1) M; accumulated in registers,
//          written to LDS interleaved [col][4 rows] with bank swizzle.
// Phase B: S[r][j] = sum_{k in adj2(j)} T1[r][k] via one ds_read_b128/edge.
//          s_new = (1-a)*Ht + a*q*S; writes bf16 M (default), fp32 M
//          (out32=1, penultimate iter), or s_new to sout (last iter).
// Precision schedule: iters 0-7 bf16->bf16, iter 8 bf16->fp32, iter 9
// fp32->sout. Dropping only the LAST quantization removes the undamped
// dominant error term (bf16-everywhere missed threshold by 5%).
// --------------------------------------------------------------------------
__global__ __launch_bounds__(256) void k_iter(
    const unsigned short* __restrict__ idx1, const int* __restrict__ cnt1,
    const unsigned short* __restrict__ idx2T, const int* __restrict__ cnt2,
    const unsigned short* __restrict__ Min, const float* __restrict__ MinF,
    const float* __restrict__ q, const float* __restrict__ Ht,
    unsigned short* __restrict__ Mout, float* __restrict__ MoutF,
    float* __restrict__ sout, int in32, int out32, int last) {
  __shared__ float lds[4 * NMAT + 32];  // swizzled max index 8216+4
  int i0 = blockIdx.x * 4;
  int tid = threadIdx.x;
  int c0 = tid * 8;  // this thread's 8 columns in phase A

  float acc[4][8];
#pragma unroll
  for (int r = 0; r < 4; ++r) {
    int i = i0 + r;
    int nn = cnt1[i];
    const unsigned short* ip = idx1 + i * CAP;
    float a[8] = {0.f, 0.f, 0.f, 0.f, 0.f, 0.f, 0.f, 0.f};
    if (in32) {
      for (int t = 0; t < nn; ++t) {
        int ka = ip[t];
        const float4* mp = (const float4*)(MinF + (size_t)ka * NMAT + c0);
        float4 v0 = mp[0];
        float4 v1 = mp[1];
        a[0] += v0.x; a[1] += v0.y; a[2] += v0.z; a[3] += v0.w;
        a[4] += v1.x; a[5] += v1.y; a[6] += v1.z; a[7] += v1.w;
      }
    } else {
      int t = 0;
      for (; t + 2 <= nn; t += 2) {
        unsigned pr = *(const unsigned*)(ip + t);  // uniform, 4B-aligned
        int ka = pr & 0xffff;
        int kb = pr >> 16;
        ushort8v va = *(const ushort8v*)(Min + (size_t)ka * NMAT + c0);
        ushort8v vb = *(const ushort8v*)(Min + (size_t)kb * NMAT + c0);
#pragma unroll
        for (int e = 0; e < 8; ++e) a[e] += bf2f(va[e]);
#pragma unroll
        for (int e = 0; e < 8; ++e) a[e] += bf2f(vb[e]);
      }
      if (t < nn) {
        int ka = ip[t];
        ushort8v va = *(const ushort8v*)(Min + (size_t)ka * NMAT + c0);
#pragma unroll
        for (int e = 0; e < 8; ++e) a[e] += bf2f(va[e]);
      }
    }
#pragma unroll
    for (int e = 0; e < 8; ++e) acc[r][e] = a[e];
  }
#pragma unroll
  for (int cc = 0; cc < 8; ++cc) {
    float4 v = make_float4(acc[0][cc], acc[1][cc], acc[2][cc], acc[3][cc]);
    *(float4*)&lds[swz(c0 + cc)] = v;  // b128, bank-balanced via swizzle
  }
  __syncthreads();

  const float alpha = 0.82f;
  const float oma = 1.0f - alpha;
#pragma unroll
  for (int jj = 0; jj < 8; ++jj) {
    int j = jj * 256 + tid;
    int nn = cnt2[j];
    const unsigned short* ip = idx2T + j;
    float s0 = 0.f, s1 = 0.f, s2 = 0.f, s3 = 0.f;
    float u0 = 0.f, u1 = 0.f, u2 = 0.f, u3 = 0.f;
    int t = 0;
    for (; t + 2 <= nn; t += 2) {
      int ka = ip[(size_t)t * NMAT];
      int kb = ip[(size_t)(t + 1) * NMAT];
      float4 va = *(const float4*)&lds[swz(ka)];
      float4 vb = *(const float4*)&lds[swz(kb)];
      s0 += va.x; s1 += va.y; s2 += va.z; s3 += va.w;
      u0 += vb.x; u1 += vb.y; u2 += vb.z; u3 += vb.w;
    }
    if (t < nn) {
      int ka = ip[(size_t)t * NMAT];
      float4 va = *(const float4*)&lds[swz(ka)];
      s0 += va.x; s1 += va.y; s2 += va.z; s3 += va.w;
    }
    float sa[4] = {s0 + u0, s1 + u1, s2 + u2, s3 + u3};
#pragma unroll
    for (int r = 0; r < 4; ++r) {
      size_t off = (size_t)(i0 + r) * NMAT + j;
      float qv = q[off];
      float sv = oma * Ht[off] + alpha * qv * sa[r];
      if (last) sout[off] = sv;
      else if (out32) MoutF[off] = qv * sv;
      else Mout[off] = f2bf(qv * sv);
    }
  }
}

extern "C" void kernel_launch(void* const* d_in, const int* in_sizes, int n_in,
                              void* d_out, int out_size, void* d_ws,
                              size_t ws_size, hipStream_t stream) {
  const float* A1 = (const float*)d_in[0];
  const float* A2 = (const float*)d_in[1];
  const float* N1 = (const float*)d_in[2];
  const float* N2 = (const float*)d_in[3];
  const float* H = (const float*)d_in[4];
  float* s_out = (float*)d_out;

  char* p = (char*)d_ws;
  auto take = [&](size_t bytes) {
    char* r = p;
    p += (bytes + 255) & ~(size_t)255;
    return r;
  };
  unsigned short* idx1 = (unsigned short*)take((size_t)NMAT * CAP * 2);
  unsigned short* idx2 = (unsigned short*)take((size_t)NMAT * CAP * 2);
  unsigned short* idx2T = (unsigned short*)take((size_t)CAP * NMAT * 2);
  int* cnt1 = (int*)take((size_t)NMAT * 4);
  int* cnt2 = (int*)take((size_t)NMAT * 4);
  float* N1n = (float*)take((size_t)NMAT * KATTR * 4);
  float* N2n = (float*)take((size_t)NMAT * KATTR * 4);
  float* C1 = (float*)take((size_t)NMAT * KATTR * 4);
  float* C2 = (float*)take((size_t)NMAT * KATTR * 4);
  float* Ht = (float*)take((size_t)NMAT * NMAT * 4);
  float* q = (float*)take((size_t)NMAT * NMAT * 4);
  unsigned short* Mb0 = (unsigned short*)take((size_t)NMAT * NMAT * 2);
  unsigned short* Mb1 = (unsigned short*)take((size_t)NMAT * NMAT * 2);
  float* Mf = (float*)take((size_t)NMAT * NMAT * 4);
  if ((size_t)(p - (char*)d_ws) > ws_size) return;

  k_build<<<NMAT, 256, 0, stream>>>(A1, idx1, (unsigned short*)nullptr, cnt1);
  k_build<<<NMAT, 256, 0, stream>>>(A2, idx2, idx2T, cnt2);
  k_norm<<<NMAT / 4, 256, 0, stream>>>(N1, N1n);
  k_norm<<<NMAT / 4, 256, 0, stream>>>(N2, N2n);
  k_gatherN<<<NMAT, 64, 0, stream>>>(idx1, cnt1, N1n, C1);
  k_gatherN<<<NMAT, 64, 0, stream>>>(idx2, cnt2, N2n, C2);
  k_transpose<<<dim3(32, 32), 256, 0, stream>>>(H, Ht);
  k_q<<<dim3(32, 32), 256, 0, stream>>>(N1n, C1, N2n, C2, Ht, q, Mb0);
  for (int it = 0; it < NITER; ++it) {
    const unsigned short* Min = (it & 1) ? Mb1 : Mb0;
    unsigned short* Mout = (it & 1) ? Mb0 : Mb1;
    int in32 = (it == NITER - 1) ? 1 : 0;
    int out32 = (it == NITER - 2) ? 1 : 0;
    int last = (it == NITER - 1) ? 1 : 0;
    k_iter<<<NMAT / 4, 256, 0, stream>>>(idx1, cnt1, idx2T, cnt2, Min, Mf, q,
                                         Ht, Mout, Mf, s_out, in32, out32,
                                         last);
  }
}

// Round 5
// 566.945 us; speedup vs baseline: 1.2032x; 1.2032x over previous
//
#include <hip/hip_runtime.h>

#define NMAT 2048
#define KATTR 64
#define CAP 128
#define NITER 10
#define NCHUNK 8
#define CW 256  // columns per chunk; bf16 M slice = 2048*256*2B = 1 MB (L2-resident)

typedef unsigned short ushort8v __attribute__((ext_vector_type(8)));
typedef unsigned short ushort4v __attribute__((ext_vector_type(4)));

// bf16 round-to-nearest-even (values finite here)
__device__ __forceinline__ unsigned short f2bf(float f) {
  unsigned u = __float_as_uint(f);
  return (unsigned short)((u + 0x7fff + ((u >> 16) & 1)) >> 16);
}
__device__ __forceinline__ float bf2f(unsigned short b) {
  return __uint_as_float((unsigned)b << 16);
}
// swizzled LDS dword index for 4-row interleaved T1 tile (proven in R4):
// bank-balanced transposed b128 writes, ~uniform random b128 gathers.
__device__ __forceinline__ int swz(int c) { return 4 * c + (((c >> 3) & 7) << 2); }

// --------------------------------------------------------------------------
// Build padded adjacency (ELL) for pattern(A); B == (A!=0), symmetric.
// --------------------------------------------------------------------------
__global__ __launch_bounds__(256) void k_build(
    const float* __restrict__ A, unsigned short* __restrict__ idx,
    unsigned short* __restrict__ idxT, int* __restrict__ cnt) {
  __shared__ int lcnt;
  int r = blockIdx.x;
  if (threadIdx.x == 0) lcnt = 0;
  __syncthreads();
  const float* row = A + (size_t)r * NMAT;
  for (int c = threadIdx.x; c < NMAT; c += 256) {
    if (row[c] != 0.0f) {
      int p = atomicAdd(&lcnt, 1);
      if (p < CAP) {
        idx[r * CAP + p] = (unsigned short)c;
        if (idxT) idxT[(size_t)p * NMAT + r] = (unsigned short)c;
      }
    }
  }
  __syncthreads();
  if (threadIdx.x == 0) cnt[r] = lcnt < CAP ? lcnt : CAP;
}

__global__ __launch_bounds__(256) void k_norm(const float* __restrict__ Nin,
                                              float* __restrict__ Nout) {
  int row = blockIdx.x * 4 + (threadIdx.x >> 6);
  int lane = threadIdx.x & 63;
  float v = Nin[(size_t)row * KATTR + lane];
  float ss = v * v;
#pragma unroll
  for (int o = 32; o > 0; o >>= 1) ss += __shfl_xor(ss, o);
  float nrm = sqrtf(ss);
  Nout[(size_t)row * KATTR + lane] = (nrm > 0.f) ? v / nrm : 0.f;
}

__global__ void k_gatherN(const unsigned short* __restrict__ idx,
                          const int* __restrict__ cnt,
                          const float* __restrict__ Nn,
                          float* __restrict__ C) {
  int i = blockIdx.x;
  int lane = threadIdx.x;  // blockDim = 64
  int nn = cnt[i];
  const unsigned short* ip = idx + i * CAP;
  float acc = 0.f;
  for (int t = 0; t < nn; ++t) {
    int k = ip[t];
    acc += Nn[(size_t)k * KATTR + lane];
  }
  C[(size_t)i * KATTR + lane] = acc;
}

__global__ __launch_bounds__(256) void k_transpose(const float* __restrict__ H,
                                                   float* __restrict__ Ht) {
  __shared__ float tile[64][65];
  int j0 = blockIdx.x * 64;
  int i0 = blockIdx.y * 64;
  int c = threadIdx.x & 63;
  int r0 = threadIdx.x >> 6;
  for (int r = r0; r < 64; r += 4)
    tile[r][c] = H[(size_t)(j0 + r) * NMAT + i0 + c];
  __syncthreads();
  for (int r = r0; r < 64; r += 4)
    Ht[(size_t)(i0 + r) * NMAT + j0 + c] = tile[c][r];
}

// --------------------------------------------------------------------------
// q = Nm>0&dm>0 ? Nm*rsqrt(Nm*dm) : 0; M0 = bf16(q*Ht).
// --------------------------------------------------------------------------
__global__ __launch_bounds__(256) void k_q(
    const float* __restrict__ N1n, const float* __restrict__ C1,
    const float* __restrict__ N2n, const float* __restrict__ C2,
    const float* __restrict__ Ht, float* __restrict__ q,
    unsigned short* __restrict__ M) {
  __shared__ float sA[64][68];
  __shared__ float sB[64][68];
  int i0 = blockIdx.y * 64, j0 = blockIdx.x * 64;
  int c = threadIdx.x & 63, r0 = threadIdx.x >> 6;
  int tx = threadIdx.x & 15, ty = threadIdx.x >> 4;

  float nmv[4][4] = {};
  float dmv[4][4] = {};

  for (int r = r0; r < 64; r += 4) {
    sA[c][r] = N1n[(size_t)(i0 + r) * KATTR + c];
    sB[c][r] = N2n[(size_t)(j0 + r) * KATTR + c];
  }
  __syncthreads();
#pragma unroll 4
  for (int k = 0; k < 64; ++k) {
    float4 a = *(const float4*)&sA[k][ty * 4];
    float4 b = *(const float4*)&sB[k][tx * 4];
    float av[4] = {a.x, a.y, a.z, a.w};
    float bv[4] = {b.x, b.y, b.z, b.w};
#pragma unroll
    for (int ii = 0; ii < 4; ++ii)
#pragma unroll
      for (int jj = 0; jj < 4; ++jj)
        nmv[ii][jj] = fmaf(av[ii], bv[jj], nmv[ii][jj]);
  }
  __syncthreads();
  for (int r = r0; r < 64; r += 4) {
    sA[c][r] = C1[(size_t)(i0 + r) * KATTR + c];
    sB[c][r] = C2[(size_t)(j0 + r) * KATTR + c];
  }
  __syncthreads();
#pragma unroll 4
  for (int k = 0; k < 64; ++k) {
    float4 a = *(const float4*)&sA[k][ty * 4];
    float4 b = *(const float4*)&sB[k][tx * 4];
    float av[4] = {a.x, a.y, a.z, a.w};
    float bv[4] = {b.x, b.y, b.z, b.w};
#pragma unroll
    for (int ii = 0; ii < 4; ++ii)
#pragma unroll
      for (int jj = 0; jj < 4; ++jj)
        dmv[ii][jj] = fmaf(av[ii], bv[jj], dmv[ii][jj]);
  }

#pragma unroll
  for (int ii = 0; ii < 4; ++ii) {
    int i = i0 + ty * 4 + ii;
    size_t base = (size_t)i * NMAT + j0 + tx * 4;
    float4 hv = *(const float4*)&Ht[base];
    float hvv[4] = {hv.x, hv.y, hv.z, hv.w};
    float qv[4];
    ushort4v mv;
#pragma unroll
    for (int jj = 0; jj < 4; ++jj) {
      float nmx = nmv[ii][jj];
      float D = nmx * dmv[ii][jj];
      float qq = (D > 0.f) ? nmx * rsqrtf(D) : 0.f;
      qv[jj] = qq;
      mv[jj] = f2bf(qq * hvv[jj]);
    }
    *(float4*)&q[base] = make_float4(qv[0], qv[1], qv[2], qv[3]);
    *(ushort4v*)&M[base] = mv;
  }
}

// --------------------------------------------------------------------------
// k1v: T1 = B1 @ M, XCD-chunked (chunk = blockIdx%8 -> per-XCD 1 MB bf16
// slice of M stays L2-resident). Wave per row, lane covers 4 cols of the
// 256-col chunk. 4-edge unroll -> 4 independent loads in flight.
// in32: gather from fp32 Mf (last iteration).
// --------------------------------------------------------------------------
__global__ __launch_bounds__(256) void k1v(
    const unsigned short* __restrict__ idx1, const int* __restrict__ cnt1,
    const unsigned short* __restrict__ Min, const float* __restrict__ MinF,
    float* __restrict__ T1, int in32) {
  int c = blockIdx.x & (NCHUNK - 1);
  int rg = blockIdx.x >> 3;
  int w = threadIdx.x >> 6, lane = threadIdx.x & 63;
  int i = rg * 4 + w;
  int nn = cnt1[i];
  const unsigned short* ip = idx1 + i * CAP;
  size_t coff = (size_t)c * CW + (size_t)lane * 4;
  float a0 = 0.f, a1 = 0.f, a2 = 0.f, a3 = 0.f;
  if (in32) {
    int t = 0;
    for (; t + 4 <= nn; t += 4) {
      uint2 pk = *(const uint2*)(ip + t);
      int k0 = pk.x & 0xffff, k1 = pk.x >> 16;
      int k2 = pk.y & 0xffff, k3 = pk.y >> 16;
      float4 v0 = *(const float4*)(MinF + (size_t)k0 * NMAT + coff);
      float4 v1 = *(const float4*)(MinF + (size_t)k1 * NMAT + coff);
      float4 v2 = *(const float4*)(MinF + (size_t)k2 * NMAT + coff);
      float4 v3 = *(const float4*)(MinF + (size_t)k3 * NMAT + coff);
      a0 += v0.x + v1.x + v2.x + v3.x;
      a1 += v0.y + v1.y + v2.y + v3.y;
      a2 += v0.z + v1.z + v2.z + v3.z;
      a3 += v0.w + v1.w + v2.w + v3.w;
    }
    for (; t < nn; ++t) {
      float4 v0 = *(const float4*)(MinF + (size_t)ip[t] * NMAT + coff);
      a0 += v0.x; a1 += v0.y; a2 += v0.z; a3 += v0.w;
    }
  } else {
    int t = 0;
    for (; t + 4 <= nn; t += 4) {
      uint2 pk = *(const uint2*)(ip + t);  // 8B-aligned (t%4==0)
      int k0 = pk.x & 0xffff, k1 = pk.x >> 16;
      int k2 = pk.y & 0xffff, k3 = pk.y >> 16;
      ushort4v v0 = *(const ushort4v*)(Min + (size_t)k0 * NMAT + coff);
      ushort4v v1 = *(const ushort4v*)(Min + (size_t)k1 * NMAT + coff);
      ushort4v v2 = *(const ushort4v*)(Min + (size_t)k2 * NMAT + coff);
      ushort4v v3 = *(const ushort4v*)(Min + (size_t)k3 * NMAT + coff);
      a0 += bf2f(v0[0]) + bf2f(v1[0]) + bf2f(v2[0]) + bf2f(v3[0]);
      a1 += bf2f(v0[1]) + bf2f(v1[1]) + bf2f(v2[1]) + bf2f(v3[1]);
      a2 += bf2f(v0[2]) + bf2f(v1[2]) + bf2f(v2[2]) + bf2f(v3[2]);
      a3 += bf2f(v0[3]) + bf2f(v1[3]) + bf2f(v2[3]) + bf2f(v3[3]);
    }
    for (; t < nn; ++t) {
      ushort4v v0 = *(const ushort4v*)(Min + (size_t)ip[t] * NMAT + coff);
      a0 += bf2f(v0[0]); a1 += bf2f(v0[1]);
      a2 += bf2f(v0[2]); a3 += bf2f(v0[3]);
    }
  }
  *(float4*)(T1 + (size_t)i * NMAT + coff) = make_float4(a0, a1, a2, a3);
}

// --------------------------------------------------------------------------
// k2v: S = T1 @ B2^T via swizzled-interleaved LDS (one ds_read_b128/edge),
// fused with s_new = (1-a)*Ht + a*q*S, M = bf16/fp32(q*s_new) or sout.
// Grid 1024: block = (rowgroup rg, j-half jh) -> 16 waves/CU.
// --------------------------------------------------------------------------
__global__ __launch_bounds__(256) void k2v(
    const unsigned short* __restrict__ idx2T, const int* __restrict__ cnt2,
    const float* __restrict__ T1, const float* __restrict__ q,
    const float* __restrict__ Ht, unsigned short* __restrict__ Mout,
    float* __restrict__ MoutF, float* __restrict__ sout, int out32,
    int last) {
  __shared__ float lds[4 * NMAT + 32];
  int rg = blockIdx.x >> 1;
  int jh = blockIdx.x & 1;
  int i0 = rg * 4;
  int tid = threadIdx.x;
  int c0 = tid * 8;
  // stage T1 tile transposed into swizzled interleaved LDS
  float4 ra[4], rb[4];
#pragma unroll
  for (int r = 0; r < 4; ++r) {
    const float* tr = T1 + (size_t)(i0 + r) * NMAT + c0;
    ra[r] = *(const float4*)tr;
    rb[r] = *(const float4*)(tr + 4);
  }
  *(float4*)&lds[swz(c0 + 0)] = make_float4(ra[0].x, ra[1].x, ra[2].x, ra[3].x);
  *(float4*)&lds[swz(c0 + 1)] = make_float4(ra[0].y, ra[1].y, ra[2].y, ra[3].y);
  *(float4*)&lds[swz(c0 + 2)] = make_float4(ra[0].z, ra[1].z, ra[2].z, ra[3].z);
  *(float4*)&lds[swz(c0 + 3)] = make_float4(ra[0].w, ra[1].w, ra[2].w, ra[3].w);
  *(float4*)&lds[swz(c0 + 4)] = make_float4(rb[0].x, rb[1].x, rb[2].x, rb[3].x);
  *(float4*)&lds[swz(c0 + 5)] = make_float4(rb[0].y, rb[1].y, rb[2].y, rb[3].y);
  *(float4*)&lds[swz(c0 + 6)] = make_float4(rb[0].z, rb[1].z, rb[2].z, rb[3].z);
  *(float4*)&lds[swz(c0 + 7)] = make_float4(rb[0].w, rb[1].w, rb[2].w, rb[3].w);
  __syncthreads();

  const float alpha = 0.82f;
  const float oma = 1.0f - alpha;
#pragma unroll
  for (int jj = 0; jj < 4; ++jj) {
    int j = jh * 1024 + jj * 256 + tid;
    int nn = cnt2[j];
    const unsigned short* ip = idx2T + j;
    float s0 = 0.f, s1 = 0.f, s2 = 0.f, s3 = 0.f;
    float u0 = 0.f, u1 = 0.f, u2 = 0.f, u3 = 0.f;
    int t = 0;
    for (; t + 2 <= nn; t += 2) {
      int ka = ip[(size_t)t * NMAT];
      int kb = ip[(size_t)(t + 1) * NMAT];
      float4 va = *(const float4*)&lds[swz(ka)];
      float4 vb = *(const float4*)&lds[swz(kb)];
      s0 += va.x; s1 += va.y; s2 += va.z; s3 += va.w;
      u0 += vb.x; u1 += vb.y; u2 += vb.z; u3 += vb.w;
    }
    if (t < nn) {
      int ka = ip[(size_t)t * NMAT];
      float4 va = *(const float4*)&lds[swz(ka)];
      s0 += va.x; s1 += va.y; s2 += va.z; s3 += va.w;
    }
    float sa[4] = {s0 + u0, s1 + u1, s2 + u2, s3 + u3};
#pragma unroll
    for (int r = 0; r < 4; ++r) {
      size_t off = (size_t)(i0 + r) * NMAT + j;
      float qv = q[off];
      float sv = oma * Ht[off] + alpha * qv * sa[r];
      if (last) sout[off] = sv;
      else if (out32) MoutF[off] = qv * sv;
      else Mout[off] = f2bf(qv * sv);
    }
  }
}

extern "C" void kernel_launch(void* const* d_in, const int* in_sizes, int n_in,
                              void* d_out, int out_size, void* d_ws,
                              size_t ws_size, hipStream_t stream) {
  const float* A1 = (const float*)d_in[0];
  const float* A2 = (const float*)d_in[1];
  const float* N1 = (const float*)d_in[2];
  const float* N2 = (const float*)d_in[3];
  const float* H = (const float*)d_in[4];
  float* s_out = (float*)d_out;

  char* p = (char*)d_ws;
  auto take = [&](size_t bytes) {
    char* r = p;
    p += (bytes + 255) & ~(size_t)255;
    return r;
  };
  unsigned short* idx1 = (unsigned short*)take((size_t)NMAT * CAP * 2);
  unsigned short* idx2 = (unsigned short*)take((size_t)NMAT * CAP * 2);
  unsigned short* idx2T = (unsigned short*)take((size_t)CAP * NMAT * 2);
  int* cnt1 = (int*)take((size_t)NMAT * 4);
  int* cnt2 = (int*)take((size_t)NMAT * 4);
  float* N1n = (float*)take((size_t)NMAT * KATTR * 4);
  float* N2n = (float*)take((size_t)NMAT * KATTR * 4);
  float* C1 = (float*)take((size_t)NMAT * KATTR * 4);
  float* C2 = (float*)take((size_t)NMAT * KATTR * 4);
  float* Ht = (float*)take((size_t)NMAT * NMAT * 4);
  float* q = (float*)take((size_t)NMAT * NMAT * 4);
  unsigned short* Mb0 = (unsigned short*)take((size_t)NMAT * NMAT * 2);
  unsigned short* Mb1 = (unsigned short*)take((size_t)NMAT * NMAT * 2);
  float* Mf = (float*)take((size_t)NMAT * NMAT * 4);
  float* T1 = (float*)take((size_t)NMAT * NMAT * 4);
  if ((size_t)(p - (char*)d_ws) > ws_size) return;

  k_build<<<NMAT, 256, 0, stream>>>(A1, idx1, (unsigned short*)nullptr, cnt1);
  k_build<<<NMAT, 256, 0, stream>>>(A2, idx2, idx2T, cnt2);
  k_norm<<<NMAT / 4, 256, 0, stream>>>(N1, N1n);
  k_norm<<<NMAT / 4, 256, 0, stream>>>(N2, N2n);
  k_gatherN<<<NMAT, 64, 0, stream>>>(idx1, cnt1, N1n, C1);
  k_gatherN<<<NMAT, 64, 0, stream>>>(idx2, cnt2, N2n, C2);
  k_transpose<<<dim3(32, 32), 256, 0, stream>>>(H, Ht);
  k_q<<<dim3(32, 32), 256, 0, stream>>>(N1n, C1, N2n, C2, Ht, q, Mb0);
  for (int it = 0; it < NITER; ++it) {
    const unsigned short* Min = (it & 1) ? Mb1 : Mb0;
    unsigned short* Mout = (it & 1) ? Mb0 : Mb1;
    int in32 = (it == NITER - 1) ? 1 : 0;
    int out32 = (it == NITER - 2) ? 1 : 0;
    int last = (it == NITER - 1) ? 1 : 0;
    k1v<<<NCHUNK * (NMAT / 4), 256, 0, stream>>>(idx1, cnt1, Min, Mf, T1,
                                                 in32);
    k2v<<<2 * (NMAT / 4), 256, 0, stream>>>(idx2T, cnt2, T1, q, Ht, Mout, Mf,
                                            s_out, out32, last);
  }
}